// Round 1
// baseline (594.184 us; speedup 1.0000x reference)
//
#include <hip/hip_runtime.h>
#include <hip/hip_bf16.h>

#define N_PTS 50000
#define H_NB 32
#define K_KP 15
#define C_IN 64
#define C_OUT 128
#define M_TILE 32
#define MPAD 40   // padded M for bf16 wfT rows: 80B rows, keeps 16B-aligned 8-elem subreads
#define BN_EPS 1e-5f
#define SLOPE 0.2f

__device__ __forceinline__ float bfl(unsigned int u){ return __uint_as_float(u << 16); }
__device__ __forceinline__ float bfh(unsigned int u){ return __uint_as_float(u & 0xffff0000u); }
__device__ __forceinline__ unsigned short f2bf(float f){
  unsigned int u = __float_as_uint(f);
  u += 0x7fffu + ((u >> 16) & 1u);   // round-nearest-even
  return (unsigned short)(u >> 16);
}

__global__ void zero_stats_kernel(float* stats){
  int t = threadIdx.x;
  if (t < 2*C_OUT) stats[t] = 0.f;
}

__global__ __launch_bounds__(512, 2) void kpconv_kernel(
    const float* __restrict__ points,
    const float* __restrict__ x,
    const int*   __restrict__ neighbors,
    const float* __restrict__ kpts,
    const float* __restrict__ weights,
    float* __restrict__ out_pre,
    float* __restrict__ stats)
{
  // LDS budget: 76800 + 32768 + 16384 + 256 + 2048 + 2048 = 130304 B (~127 KiB) -> 1 block/CU, 8 waves
  __shared__ unsigned short wfT[K_KP*C_IN*MPAD];   // [k][c][m] bf16
  __shared__ float Wk[C_IN*C_OUT];                 // [c][d] staged per k
  __shared__ float infl[8*H_NB*16];                // per-wave [h][k] (k padded to 16)
  __shared__ float kpl[16*4];                      // kernel points as float4
  __shared__ float ssum[4][C_OUT];
  __shared__ float ssq[4][C_OUT];

  const int tid  = threadIdx.x;
  const int w    = tid >> 6;
  const int lane = tid & 63;
  const int base = blockIdx.x * M_TILE;

  if (tid < 64) {
    int k = tid >> 2, comp = tid & 3;
    kpl[tid] = (k < K_KP && comp < 3) ? kpts[k*3+comp] : 0.f;
  }
  __syncthreads();

  float* inflw = &infl[w * H_NB * 16];

  // ---------------- Phase A: influence + gather -> wf (regs, lane=c) -> LDS bf16 ----------------
  for (int i = 0; i < 4; ++i) {
    const int m = w*4 + i;
    const int n = base + m;
    float wf[K_KP];
    #pragma unroll
    for (int k = 0; k < K_KP; ++k) wf[k] = 0.f;

    if (n < N_PTS) {
      const int idx = neighbors[n*H_NB + (lane & 31)];
      const float cx = points[n*3+0];
      const float cy = points[n*3+1];
      const float cz = points[n*3+2];
      // lane-parallel influence over 480 (h,k) pairs
      #pragma unroll
      for (int it = 0; it < 8; ++it) {
        int p = it*64 + lane;
        if (p < H_NB*K_KP) {
          int h = p / K_KP;
          int k = p - h*K_KP;
          int nh = __shfl(idx, h);
          float dx = points[nh*3+0] - cx - kpl[k*4+0];
          float dy = points[nh*3+1] - cy - kpl[k*4+1];
          float dz = points[nh*3+2] - cz - kpl[k*4+2];
          float d2 = dx*dx + dy*dy + dz*dz;
          float f = 1.f - sqrtf(d2);
          inflw[h*16 + k] = f > 0.f ? f : 0.f;
        }
      }
      // wave-local LDS visibility (writes by other lanes of this wave)
      asm volatile("s_waitcnt lgkmcnt(0)" ::: "memory");
      #pragma unroll 8
      for (int h = 0; h < H_NB; ++h) {
        int nh = __shfl(idx, h);
        float xv = x[nh*C_IN + lane];
        const float4* ir = (const float4*)&inflw[h*16];
        float4 i0 = ir[0], i1 = ir[1], i2 = ir[2], i3 = ir[3];
        wf[0]  += i0.x*xv; wf[1]  += i0.y*xv; wf[2]  += i0.z*xv; wf[3]  += i0.w*xv;
        wf[4]  += i1.x*xv; wf[5]  += i1.y*xv; wf[6]  += i1.z*xv; wf[7]  += i1.w*xv;
        wf[8]  += i2.x*xv; wf[9]  += i2.y*xv; wf[10] += i2.z*xv; wf[11] += i2.w*xv;
        wf[12] += i3.x*xv; wf[13] += i3.y*xv; wf[14] += i3.z*xv;
      }
    }
    #pragma unroll
    for (int k = 0; k < K_KP; ++k)
      wfT[(k*C_IN + lane)*MPAD + m] = f2bf(wf[k]);
  }

  // ---------------- Phase B: out[m][d] = sum_{k,c} wf[k][c][m] * W[k][c][d] ----------------
  float acc[8];
  #pragma unroll
  for (int j = 0; j < 8; ++j) acc[j] = 0.f;
  const int d    = tid & (C_OUT-1);
  const int mrow = tid >> 7;        // 0..3 -> m = mrow*8 + j

  for (int k = 0; k < K_KP; ++k) {
    __syncthreads();  // protect Wk overwrite (and, first iter, wfT completion)
    {
      const float4* Wg = (const float4*)(weights + k*C_IN*C_OUT);
      float4* Ws = (float4*)Wk;
      #pragma unroll
      for (int t = 0; t < 4; ++t)
        Ws[tid + t*512] = Wg[tid + t*512];
    }
    __syncthreads();
    const unsigned short* wrow = &wfT[k*C_IN*MPAD + mrow*8];
    #pragma unroll 8
    for (int c = 0; c < C_IN; ++c) {
      float wv = Wk[c*C_OUT + d];
      uint4 u = *(const uint4*)(wrow + c*MPAD);   // 8 bf16 (wave-uniform broadcast)
      acc[0] += bfl(u.x)*wv; acc[1] += bfh(u.x)*wv;
      acc[2] += bfl(u.y)*wv; acc[3] += bfh(u.y)*wv;
      acc[4] += bfl(u.z)*wv; acc[5] += bfh(u.z)*wv;
      acc[6] += bfl(u.w)*wv; acc[7] += bfh(u.w)*wv;
    }
  }

  // ---------------- Epilogue: store pre-BN + block-reduced stats ----------------
  float s = 0.f, s2 = 0.f;
  #pragma unroll
  for (int j = 0; j < 8; ++j) {
    int m = mrow*8 + j;
    int n = base + m;
    if (n < N_PTS) {
      out_pre[(size_t)n*C_OUT + d] = acc[j];
      s  += acc[j];
      s2 += acc[j]*acc[j];
    }
  }
  ssum[mrow][d] = s;
  ssq[mrow][d]  = s2;
  __syncthreads();
  if (tid < C_OUT) {
    float a = ssum[0][tid]+ssum[1][tid]+ssum[2][tid]+ssum[3][tid];
    float b = ssq[0][tid]+ssq[1][tid]+ssq[2][tid]+ssq[3][tid];
    atomicAdd(&stats[tid], a);
    atomicAdd(&stats[C_OUT + tid], b);
  }
}

__global__ void finalize_kernel(const float* __restrict__ stats,
                                const float* __restrict__ gamma,
                                const float* __restrict__ beta,
                                float* __restrict__ sc_sh){
  int d = threadIdx.x;
  if (d < C_OUT) {
    float mean = stats[d] * (1.f/N_PTS);
    float var  = stats[C_OUT+d] * (1.f/N_PTS) - mean*mean;
    var = var > 0.f ? var : 0.f;
    float inv = rsqrtf(var + BN_EPS);
    float sc  = inv * gamma[d];
    sc_sh[d]        = sc;
    sc_sh[C_OUT+d]  = beta[d] - mean * sc;
  }
}

__global__ __launch_bounds__(256) void bn_lrelu_kernel(float* __restrict__ out,
                                                       const float* __restrict__ sc_sh){
  const int total4 = N_PTS*C_OUT/4;
  const float4* scp = (const float4*)sc_sh;
  const float4* shp = (const float4*)(sc_sh + C_OUT);
  float4* o4 = (float4*)out;
  for (int t = blockIdx.x*blockDim.x + threadIdx.x; t < total4; t += gridDim.x*blockDim.x) {
    int col4 = t & (C_OUT/4 - 1);
    float4 v = o4[t];
    float4 sc = scp[col4], sh = shp[col4];
    float y0 = v.x*sc.x + sh.x;
    float y1 = v.y*sc.y + sh.y;
    float y2 = v.z*sc.z + sh.z;
    float y3 = v.w*sc.w + sh.w;
    v.x = y0 > 0.f ? y0 : SLOPE*y0;
    v.y = y1 > 0.f ? y1 : SLOPE*y1;
    v.z = y2 > 0.f ? y2 : SLOPE*y2;
    v.w = y3 > 0.f ? y3 : SLOPE*y3;
    o4[t] = v;
  }
}

extern "C" void kernel_launch(void* const* d_in, const int* in_sizes, int n_in,
                              void* d_out, int out_size, void* d_ws, size_t ws_size,
                              hipStream_t stream) {
  const float* points    = (const float*)d_in[0];
  const float* x         = (const float*)d_in[1];
  const int*   neighbors = (const int*)d_in[2];
  const float* kpts      = (const float*)d_in[3];
  const float* weights   = (const float*)d_in[4];
  const float* gamma     = (const float*)d_in[5];
  const float* beta      = (const float*)d_in[6];
  float* out = (float*)d_out;
  float* ws  = (float*)d_ws;   // [0..255] sum/sumsq, [256..511] scale/shift

  hipLaunchKernelGGL(zero_stats_kernel, dim3(1), dim3(256), 0, stream, ws);
  const int nblocks = (N_PTS + M_TILE - 1) / M_TILE;
  hipLaunchKernelGGL(kpconv_kernel, dim3(nblocks), dim3(512), 0, stream,
                     points, x, neighbors, kpts, weights, out, ws);
  hipLaunchKernelGGL(finalize_kernel, dim3(1), dim3(128), 0, stream, ws, gamma, beta, ws + 2*C_OUT);
  hipLaunchKernelGGL(bn_lrelu_kernel, dim3(2048), dim3(256), 0, stream, out, ws + 2*C_OUT);
}

// Round 4
// 238.327 us; speedup vs baseline: 2.4932x; 2.4932x over previous
//
#include <hip/hip_runtime.h>
#include <hip/hip_bf16.h>

#define N_PTS 50000
#define H_NB 32
#define K_KP 15
#define C_IN 64
#define C_OUT 128
#define M_TILE 64
#define KC 960            // K_KP * C_IN
#define WFS 968           // wf_lds row stride (bf16 elems): 960 + 8 pad -> 2-way banks, 16B aligned
#define BN_EPS 1e-5f
#define SLOPE 0.2f

typedef __attribute__((ext_vector_type(8))) __bf16 bf16x8;
typedef __attribute__((ext_vector_type(8))) unsigned short ushort8;
typedef __attribute__((ext_vector_type(4))) float f32x4;

__device__ __forceinline__ unsigned short f2bf(float f){
  unsigned int u = __float_as_uint(f);
  u += 0x7fffu + ((u >> 16) & 1u);   // round-nearest-even
  return (unsigned short)(u >> 16);
}

__global__ void zero_stats_kernel(float* stats){
  int t = threadIdx.x;
  if (t < 2*C_OUT) stats[t] = 0.f;
}

__global__ __launch_bounds__(512, 1) void kpconv_kernel(
    const float* __restrict__ points,
    const float* __restrict__ x,
    const int*   __restrict__ neighbors,
    const float* __restrict__ kpts,
    const float* __restrict__ weights,
    float* __restrict__ out_pre,
    float* __restrict__ stats)
{
  // LDS: 123904 + 16384 + 4096 + 1024 + 1024 = 146432 B -> 1 block/CU (8 waves)
  __shared__ unsigned short wf_lds[M_TILE * WFS];  // [m][k*64+c] bf16
  __shared__ float infl[8 * H_NB * 16];            // per-wave [h][k pad 16]
  __shared__ float npos[8 * H_NB * 4];             // per-wave relative neighbor pos
  __shared__ float stat_s[2][C_OUT];
  __shared__ float stat_q[2][C_OUT];

  const int tid  = threadIdx.x;
  const int w    = tid >> 6;
  const int lane = tid & 63;
  const int base = blockIdx.x * M_TILE;

  // kernel points in registers of lanes 0..14 (broadcast via shfl)
  float kx = 0.f, ky = 0.f, kz = 0.f;
  if (lane < K_KP) {
    kx = kpts[lane*3+0]; ky = kpts[lane*3+1]; kz = kpts[lane*3+2];
  }

  float* inflw = &infl[w * H_NB * 16];
  float* nposw = &npos[w * H_NB * 4];

  // ---------------- Phase A: influence + gather -> wf (regs, lane=c) -> LDS bf16 ----------------
  for (int i = 0; i < 8; ++i) {
    const int m = w*8 + i;
    const int n = base + m;
    float wf[K_KP];
    #pragma unroll
    for (int k = 0; k < K_KP; ++k) wf[k] = 0.f;

    if (n < N_PTS) {
      const int idx = neighbors[n*H_NB + (lane & 31)];
      const float cx = points[n*3+0], cy = points[n*3+1], cz = points[n*3+2];
      if (lane < 32) {
        const float* pp = points + (size_t)idx*3;
        nposw[lane*4+0] = pp[0] - cx;
        nposw[lane*4+1] = pp[1] - cy;
        nposw[lane*4+2] = pp[2] - cz;
      }
      asm volatile("s_waitcnt lgkmcnt(0)" ::: "memory");
      // lane-parallel influence over 480 (h,k) pairs
      #pragma unroll
      for (int it = 0; it < 8; ++it) {
        int p = it*64 + lane;
        if (p < H_NB*K_KP) {
          int h = p / K_KP;
          int k = p - h*K_KP;
          const float4 rp = *(const float4*)&nposw[h*4];
          float qx = __shfl(kx, k), qy = __shfl(ky, k), qz = __shfl(kz, k);
          float dx = rp.x - qx, dy = rp.y - qy, dz = rp.z - qz;
          float f = 1.f - sqrtf(dx*dx + dy*dy + dz*dz);
          inflw[h*16 + k] = f > 0.f ? f : 0.f;
        }
      }
      asm volatile("s_waitcnt lgkmcnt(0)" ::: "memory");
      #pragma unroll 8
      for (int h = 0; h < H_NB; ++h) {
        int nh = __shfl(idx, h);
        float xv = x[(size_t)nh*C_IN + lane];
        const float4* ir = (const float4*)&inflw[h*16];
        float4 i0 = ir[0], i1 = ir[1], i2 = ir[2], i3 = ir[3];
        wf[0]  += i0.x*xv; wf[1]  += i0.y*xv; wf[2]  += i0.z*xv; wf[3]  += i0.w*xv;
        wf[4]  += i1.x*xv; wf[5]  += i1.y*xv; wf[6]  += i1.z*xv; wf[7]  += i1.w*xv;
        wf[8]  += i2.x*xv; wf[9]  += i2.y*xv; wf[10] += i2.z*xv; wf[11] += i2.w*xv;
        wf[12] += i3.x*xv; wf[13] += i3.y*xv; wf[14] += i3.z*xv;
      }
    }
    #pragma unroll
    for (int k = 0; k < K_KP; ++k)
      wf_lds[m*WFS + k*C_IN + lane] = f2bf(wf[k]);
  }

  __syncthreads();

  // ---------------- Phase B: out[64x128] = wf[64x960] @ W[960x128] via MFMA ----------------
  // wave grid: wm = w>>2 (2 row-tiles of 32), wd = w&3 (4 col-tiles of 32)
  const int wm  = w >> 2;
  const int wd  = w & 3;
  const int l15 = lane & 15;
  const int lq  = lane >> 4;

  f32x4 acc00{0.f,0.f,0.f,0.f}, acc01{0.f,0.f,0.f,0.f};
  f32x4 acc10{0.f,0.f,0.f,0.f}, acc11{0.f,0.f,0.f,0.f};

  const unsigned short* arow0 = &wf_lds[(wm*32 + l15) * WFS + lq*8];
  const unsigned short* arow1 = arow0 + 16*WFS;
  const float* wg = weights + (size_t)(lq*8)*C_OUT + wd*32 + l15;

  #pragma unroll 2
  for (int ks = 0; ks < KC/32; ++ks) {
    bf16x8 a0 = __builtin_bit_cast(bf16x8, *(const uint4*)(arow0 + ks*32));
    bf16x8 a1 = __builtin_bit_cast(bf16x8, *(const uint4*)(arow1 + ks*32));
    const float* p0 = wg + (size_t)ks*32*C_OUT;
    ushort8 ub0, ub1;
    #pragma unroll
    for (int j = 0; j < 8; ++j) {
      ub0[j] = f2bf(p0[j*C_OUT]);
      ub1[j] = f2bf(p0[j*C_OUT + 16]);
    }
    bf16x8 b0 = __builtin_bit_cast(bf16x8, ub0);
    bf16x8 b1 = __builtin_bit_cast(bf16x8, ub1);
    acc00 = __builtin_amdgcn_mfma_f32_16x16x32_bf16(a0, b0, acc00, 0, 0, 0);
    acc01 = __builtin_amdgcn_mfma_f32_16x16x32_bf16(a0, b1, acc01, 0, 0, 0);
    acc10 = __builtin_amdgcn_mfma_f32_16x16x32_bf16(a1, b0, acc10, 0, 0, 0);
    acc11 = __builtin_amdgcn_mfma_f32_16x16x32_bf16(a1, b1, acc11, 0, 0, 0);
  }

  // ---------------- Epilogue: store pre-BN + block-reduced stats ----------------
  float s0 = 0.f, q0 = 0.f, s1 = 0.f, q1 = 0.f;
  const int dcol0 = wd*32 + l15;
  #pragma unroll
  for (int mi = 0; mi < 2; ++mi) {
    const f32x4 A0 = mi ? acc10 : acc00;
    const f32x4 A1 = mi ? acc11 : acc01;
    #pragma unroll
    for (int r = 0; r < 4; ++r) {
      int m = wm*32 + mi*16 + lq*4 + r;    // C/D: row = (lane>>4)*4 + reg
      int n = base + m;
      if (n < N_PTS) {
        float v0 = A0[r], v1 = A1[r];
        out_pre[(size_t)n*C_OUT + dcol0]      = v0;
        out_pre[(size_t)n*C_OUT + dcol0 + 16] = v1;
        s0 += v0; q0 += v0*v0;
        s1 += v1; q1 += v1*v1;
      }
    }
  }
  s0 += __shfl_xor(s0, 16); s0 += __shfl_xor(s0, 32);
  q0 += __shfl_xor(q0, 16); q0 += __shfl_xor(q0, 32);
  s1 += __shfl_xor(s1, 16); s1 += __shfl_xor(s1, 32);
  q1 += __shfl_xor(q1, 16); q1 += __shfl_xor(q1, 32);
  if (lane < 16) {
    stat_s[wm][wd*32 + lane]      = s0;
    stat_s[wm][wd*32 + 16 + lane] = s1;
    stat_q[wm][wd*32 + lane]      = q0;
    stat_q[wm][wd*32 + 16 + lane] = q1;
  }
  __syncthreads();
  if (tid < C_OUT) {
    atomicAdd(&stats[tid],         stat_s[0][tid] + stat_s[1][tid]);
    atomicAdd(&stats[C_OUT + tid], stat_q[0][tid] + stat_q[1][tid]);
  }
}

__global__ void finalize_kernel(const float* __restrict__ stats,
                                const float* __restrict__ gamma,
                                const float* __restrict__ beta,
                                float* __restrict__ sc_sh){
  int d = threadIdx.x;
  if (d < C_OUT) {
    float mean = stats[d] * (1.f/N_PTS);
    float var  = stats[C_OUT+d] * (1.f/N_PTS) - mean*mean;
    var = var > 0.f ? var : 0.f;
    float inv = rsqrtf(var + BN_EPS);
    float sc  = inv * gamma[d];
    sc_sh[d]        = sc;
    sc_sh[C_OUT+d]  = beta[d] - mean * sc;
  }
}

__global__ __launch_bounds__(256) void bn_lrelu_kernel(float* __restrict__ out,
                                                       const float* __restrict__ sc_sh){
  const int total4 = N_PTS*C_OUT/4;
  const float4* scp = (const float4*)sc_sh;
  const float4* shp = (const float4*)(sc_sh + C_OUT);
  float4* o4 = (float4*)out;
  for (int t = blockIdx.x*blockDim.x + threadIdx.x; t < total4; t += gridDim.x*blockDim.x) {
    int col4 = t & (C_OUT/4 - 1);
    float4 v = o4[t];
    float4 sc = scp[col4], sh = shp[col4];
    float y0 = v.x*sc.x + sh.x;
    float y1 = v.y*sc.y + sh.y;
    float y2 = v.z*sc.z + sh.z;
    float y3 = v.w*sc.w + sh.w;
    v.x = y0 > 0.f ? y0 : SLOPE*y0;
    v.y = y1 > 0.f ? y1 : SLOPE*y1;
    v.z = y2 > 0.f ? y2 : SLOPE*y2;
    v.w = y3 > 0.f ? y3 : SLOPE*y3;
    o4[t] = v;
  }
}

extern "C" void kernel_launch(void* const* d_in, const int* in_sizes, int n_in,
                              void* d_out, int out_size, void* d_ws, size_t ws_size,
                              hipStream_t stream) {
  const float* points    = (const float*)d_in[0];
  const float* x         = (const float*)d_in[1];
  const int*   neighbors = (const int*)d_in[2];
  const float* kpts      = (const float*)d_in[3];
  const float* weights   = (const float*)d_in[4];
  const float* gamma     = (const float*)d_in[5];
  const float* beta      = (const float*)d_in[6];
  float* out = (float*)d_out;
  float* ws  = (float*)d_ws;   // [0..255] sum/sumsq, [256..511] scale/shift

  hipLaunchKernelGGL(zero_stats_kernel, dim3(1), dim3(256), 0, stream, ws);
  const int nblocks = (N_PTS + M_TILE - 1) / M_TILE;
  hipLaunchKernelGGL(kpconv_kernel, dim3(nblocks), dim3(512), 0, stream,
                     points, x, neighbors, kpts, weights, out, ws);
  hipLaunchKernelGGL(finalize_kernel, dim3(1), dim3(128), 0, stream, ws, gamma, beta, ws + 2*C_OUT);
  hipLaunchKernelGGL(bn_lrelu_kernel, dim3(2048), dim3(256), 0, stream, out, ws + 2*C_OUT);
}

// Round 7
// 135.778 us; speedup vs baseline: 4.3762x; 1.7553x over previous
//
#include <hip/hip_runtime.h>
#include <hip/hip_bf16.h>

#define N_PTS 50000
#define H_NB 32
#define K_KP 15
#define C_IN 64
#define C_OUT 128
#define M_TILE 32
#define NW 4
#define PPW 8            // points per wave
#define KC 960           // K_KP * C_IN
#define WFS 968          // wf_lds row stride (bf16 elems), 16B-aligned rows
#define XG_PLANE 532     // elems per ct-plane (8 subtiles*64 + 20 pad)
#define XG_WAVE (4*XG_PLANE)
#define BN_EPS 1e-5f
#define SLOPE 0.2f

typedef __attribute__((ext_vector_type(8))) __bf16 bf16x8;
typedef __attribute__((ext_vector_type(8))) unsigned short ushort8;
typedef __attribute__((ext_vector_type(4))) float f32x4;

__device__ __forceinline__ unsigned short bfbits(float f){
  return __builtin_bit_cast(unsigned short, (__bf16)f);
}

__global__ void zero_stats_kernel(float* stats){
  int t = threadIdx.x;
  if (t < 2*C_OUT) stats[t] = 0.f;
}

__global__ __launch_bounds__(256, 2) void kpconv_kernel(
    const float* __restrict__ points,
    const float* __restrict__ x,
    const int*   __restrict__ neighbors,
    const float* __restrict__ kpts,
    const float* __restrict__ weights,
    float* __restrict__ out_pre,
    float* __restrict__ stats)
{
  // LDS: 61952 + 17024 + 512 + 512 = 80000 B -> 2 blocks/CU
  __shared__ unsigned short wf_lds[M_TILE * WFS];
  __shared__ unsigned short xg[NW * XG_WAVE];   // per-wave gathered-x, subtiled [ct][h/4][h%4][16]
  __shared__ float sh_sum[C_OUT];
  __shared__ float sh_sq[C_OUT];

  const int tid  = threadIdx.x;
  const int w    = tid >> 6;
  const int lane = tid & 63;
  const int l15  = lane & 15;
  const int lq   = lane >> 4;
  const int base = blockIdx.x * M_TILE;

  // this lane's kernel point (m = l15); m==15 -> influence forced to 0 (far sentinel)
  float kqx, kqy, kqz;
  if (l15 < K_KP) { kqx = kpts[l15*3+0]; kqy = kpts[l15*3+1]; kqz = kpts[l15*3+2]; }
  else            { kqx = 1e3f; kqy = 0.f; kqz = 0.f; }

  unsigned short* xgw = &xg[w * XG_WAVE];

  // ---------------- Phase A: per-point MFMA  wf[k][c] = infl[k][h] @ x_g[h][c] ----------------
  {
    int   idx_c, idx_n = 0, idx_nn = 0;
    float pcx, pcy, pcz, pnx = 0, pny = 0, pnz = 0;
    float ccx, ccy, ccz, cnx = 0, cny = 0, cnz = 0, c2x = 0, c2y = 0, c2z = 0;
    float4 xr[8];

    // prologue: point 0 fully issued, point 1 idx/center/npos issued
    {
      int n0 = base + w*PPW;  int nc0 = n0 < N_PTS ? n0 : N_PTS-1;
      idx_c = neighbors[nc0*H_NB + (lane & 31)];
      ccx = points[nc0*3+0]; ccy = points[nc0*3+1]; ccz = points[nc0*3+2];
      const float* pp = points + (size_t)idx_c*3;
      pcx = pp[0]; pcy = pp[1]; pcz = pp[2];
      #pragma unroll
      for (int it = 0; it < 8; ++it) {
        int h  = 4*it + lq;
        int nh = __shfl(idx_c, h);
        xr[it] = *(const float4*)&x[(size_t)nh*C_IN + 4*l15];
      }
      int n1 = base + w*PPW + 1; int nc1 = n1 < N_PTS ? n1 : N_PTS-1;
      idx_n = neighbors[nc1*H_NB + (lane & 31)];
      cnx = points[nc1*3+0]; cny = points[nc1*3+1]; cnz = points[nc1*3+2];
      const float* pq = points + (size_t)idx_n*3;
      pnx = pq[0]; pny = pq[1]; pnz = pq[2];
    }

    #pragma unroll 1
    for (int p = 0; p < PPW; ++p) {
      const int mpt = w*PPW + p;

      // influence A-frag: lane holds infl(kernel-pt m=l15, h = lq*8+j)
      float rx = pcx - ccx, ry = pcy - ccy, rz = pcz - ccz;   // lanes 0-31 meaningful
      bf16x8 afrag;
      #pragma unroll
      for (int j = 0; j < 8; ++j) {
        int h = (lq << 3) + j;
        float dx = __shfl(rx, h) - kqx;
        float dy = __shfl(ry, h) - kqy;
        float dz = __shfl(rz, h) - kqz;
        float ss = dx*dx + dy*dy + dz*dz;
        float f  = 1.f - sqrtf(ss);
        f = f > 0.f ? f : 0.f;
        afrag[j] = (__bf16)f;
      }

      // stage current point's gathered x -> LDS (bf16, subtiled [ct][h>>2][h&3][c16])
      #pragma unroll
      for (int it = 0; it < 8; ++it) {
        float4 v = xr[it];
        unsigned lo = ((unsigned)bfbits(v.y) << 16) | bfbits(v.x);
        unsigned hi = ((unsigned)bfbits(v.w) << 16) | bfbits(v.z);
        int ei = XG_PLANE*(l15 >> 2) + 64*it + 16*lq + 4*(lane & 3);
        uint2 val; val.x = lo; val.y = hi;
        *(uint2*)(xgw + ei) = val;
      }

      // issue next point's gather (1-deep pipeline)
      if (p + 1 < PPW) {
        #pragma unroll
        for (int it = 0; it < 8; ++it) {
          int h  = 4*it + lq;
          int nh = __shfl(idx_n, h);
          xr[it] = *(const float4*)&x[(size_t)nh*C_IN + 4*l15];
        }
      }
      if (p + 2 < PPW) {
        int n2 = base + w*PPW + p + 2; int nc2 = n2 < N_PTS ? n2 : N_PTS-1;
        idx_nn = neighbors[nc2*H_NB + (lane & 31)];
        c2x = points[nc2*3+0]; c2y = points[nc2*3+1]; c2z = points[nc2*3+2];
      }

      // drain staging writes (wave-local visibility + compiler barrier)
      asm volatile("s_waitcnt lgkmcnt(0)" ::: "memory");

      // B-frags via plain scalar LDS reads: lane wants xg[h = lq*8+j][c = ct*16 + l15]
      // subtiled addr: XG_PLANE*ct + 64*(h>>2) + 16*(h&3) + l15  (conflict-free: 8 dwords/8 banks)
      ushort8 bbr[4];
      #pragma unroll
      for (int ct = 0; ct < 4; ++ct) {
        #pragma unroll
        for (int j = 0; j < 8; ++j) {
          int h = lq*8 + j;
          bbr[ct][j] = xgw[XG_PLANE*ct + 64*(h>>2) + 16*(h&3) + l15];
        }
      }

      f32x4 acc[4] = {{0,0,0,0},{0,0,0,0},{0,0,0,0},{0,0,0,0}};
      #pragma unroll
      for (int ct = 0; ct < 4; ++ct) {
        bf16x8 bv = __builtin_bit_cast(bf16x8, bbr[ct]);
        acc[ct] = __builtin_amdgcn_mfma_f32_16x16x32_bf16(afrag, bv, acc[ct], 0, 0, 0);
      }

      // writeback wf rows (C layout: row k = 4*lq + r, col c = ct*16 + l15)
      #pragma unroll
      for (int ct = 0; ct < 4; ++ct) {
        #pragma unroll
        for (int r = 0; r < 4; ++r) {
          int k = 4*lq + r;
          if (k < K_KP)
            wf_lds[mpt*WFS + k*C_IN + ct*16 + l15] = bfbits(acc[ct][r]);
        }
      }

      // rotate pipeline registers; then prefetch npos for the new "next" point
      if (p + 1 < PPW) {
        pcx = pnx; pcy = pny; pcz = pnz;
        ccx = cnx; ccy = cny; ccz = cnz;
        idx_c = idx_n; idx_n = idx_nn;
        cnx = c2x; cny = c2y; cnz = c2z;
        if (p + 2 < PPW) {
          const float* pq = points + (size_t)idx_n*3;  // idx_n now = point p+2's indices
          pnx = pq[0]; pny = pq[1]; pnz = pq[2];
        }
      }
    }
  }

  __syncthreads();

  // ---------------- Phase B: out[32x128] = wf[32x960] @ W[960x128] via MFMA ----------------
  const int wd = w;   // 4 waves -> 4 col-tiles of 32
  f32x4 b00{0,0,0,0}, b01{0,0,0,0}, b10{0,0,0,0}, b11{0,0,0,0};

  const unsigned short* arow0 = &wf_lds[l15*WFS + lq*8];
  const unsigned short* arow1 = arow0 + 16*WFS;
  const float* wg = weights + (size_t)(lq*8)*C_OUT + wd*32 + l15;

  #pragma unroll 2
  for (int ks = 0; ks < KC/32; ++ks) {
    bf16x8 a0 = __builtin_bit_cast(bf16x8, *(const uint4*)(arow0 + ks*32));
    bf16x8 a1 = __builtin_bit_cast(bf16x8, *(const uint4*)(arow1 + ks*32));
    const float* p0 = wg + (size_t)ks*32*C_OUT;
    ushort8 ub0, ub1;
    #pragma unroll
    for (int j = 0; j < 8; ++j) {
      ub0[j] = bfbits(p0[j*C_OUT]);
      ub1[j] = bfbits(p0[j*C_OUT + 16]);
    }
    bf16x8 bb0 = __builtin_bit_cast(bf16x8, ub0);
    bf16x8 bb1 = __builtin_bit_cast(bf16x8, ub1);
    b00 = __builtin_amdgcn_mfma_f32_16x16x32_bf16(a0, bb0, b00, 0, 0, 0);
    b01 = __builtin_amdgcn_mfma_f32_16x16x32_bf16(a0, bb1, b01, 0, 0, 0);
    b10 = __builtin_amdgcn_mfma_f32_16x16x32_bf16(a1, bb0, b10, 0, 0, 0);
    b11 = __builtin_amdgcn_mfma_f32_16x16x32_bf16(a1, bb1, b11, 0, 0, 0);
  }

  // ---------------- Epilogue: store pre-BN + per-block stats ----------------
  float s0 = 0.f, q0 = 0.f, s1 = 0.f, q1 = 0.f;
  const int dcol0 = wd*32 + l15;
  #pragma unroll
  for (int mi = 0; mi < 2; ++mi) {
    const f32x4 A0 = mi ? b10 : b00;
    const f32x4 A1 = mi ? b11 : b01;
    #pragma unroll
    for (int r = 0; r < 4; ++r) {
      int m = mi*16 + 4*lq + r;
      int n = base + m;
      if (n < N_PTS) {
        float v0 = A0[r], v1 = A1[r];
        out_pre[(size_t)n*C_OUT + dcol0]      = v0;
        out_pre[(size_t)n*C_OUT + dcol0 + 16] = v1;
        s0 += v0; q0 += v0*v0;
        s1 += v1; q1 += v1*v1;
      }
    }
  }
  s0 += __shfl_xor(s0, 16); s0 += __shfl_xor(s0, 32);
  q0 += __shfl_xor(q0, 16); q0 += __shfl_xor(q0, 32);
  s1 += __shfl_xor(s1, 16); s1 += __shfl_xor(s1, 32);
  q1 += __shfl_xor(q1, 16); q1 += __shfl_xor(q1, 32);
  if (lane < 16) {               // each (wave, l15) owns 2 distinct columns
    sh_sum[wd*32 + lane]      = s0;
    sh_sum[wd*32 + 16 + lane] = s1;
    sh_sq [wd*32 + lane]      = q0;
    sh_sq [wd*32 + 16 + lane] = q1;
  }
  __syncthreads();
  if (tid < C_OUT) {
    atomicAdd(&stats[tid],         sh_sum[tid]);
    atomicAdd(&stats[C_OUT + tid], sh_sq[tid]);
  }
}

__global__ void finalize_kernel(const float* __restrict__ stats,
                                const float* __restrict__ gamma,
                                const float* __restrict__ beta,
                                float* __restrict__ sc_sh){
  int d = threadIdx.x;
  if (d < C_OUT) {
    float mean = stats[d] * (1.f/N_PTS);
    float var  = stats[C_OUT+d] * (1.f/N_PTS) - mean*mean;
    var = var > 0.f ? var : 0.f;
    float inv = rsqrtf(var + BN_EPS);
    float sc  = inv * gamma[d];
    sc_sh[d]        = sc;
    sc_sh[C_OUT+d]  = beta[d] - mean * sc;
  }
}

__global__ __launch_bounds__(256) void bn_lrelu_kernel(float* __restrict__ out,
                                                       const float* __restrict__ sc_sh){
  const int total4 = N_PTS*C_OUT/4;
  const float4* scp = (const float4*)sc_sh;
  const float4* shp = (const float4*)(sc_sh + C_OUT);
  float4* o4 = (float4*)out;
  for (int t = blockIdx.x*blockDim.x + threadIdx.x; t < total4; t += gridDim.x*blockDim.x) {
    int col4 = t & (C_OUT/4 - 1);
    float4 v = o4[t];
    float4 sc = scp[col4], sh = shp[col4];
    float y0 = v.x*sc.x + sh.x;
    float y1 = v.y*sc.y + sh.y;
    float y2 = v.z*sc.z + sh.z;
    float y3 = v.w*sc.w + sh.w;
    v.x = y0 > 0.f ? y0 : SLOPE*y0;
    v.y = y1 > 0.f ? y1 : SLOPE*y1;
    v.z = y2 > 0.f ? y2 : SLOPE*y2;
    v.w = y3 > 0.f ? y3 : SLOPE*y3;
    o4[t] = v;
  }
}

extern "C" void kernel_launch(void* const* d_in, const int* in_sizes, int n_in,
                              void* d_out, int out_size, void* d_ws, size_t ws_size,
                              hipStream_t stream) {
  const float* points    = (const float*)d_in[0];
  const float* x         = (const float*)d_in[1];
  const int*   neighbors = (const int*)d_in[2];
  const float* kpts      = (const float*)d_in[3];
  const float* weights   = (const float*)d_in[4];
  const float* gamma     = (const float*)d_in[5];
  const float* beta      = (const float*)d_in[6];
  float* out = (float*)d_out;
  float* ws  = (float*)d_ws;   // [0..255] sum/sumsq, [256..511] scale/shift

  hipLaunchKernelGGL(zero_stats_kernel, dim3(1), dim3(256), 0, stream, ws);
  const int nblocks = (N_PTS + M_TILE - 1) / M_TILE;
  hipLaunchKernelGGL(kpconv_kernel, dim3(nblocks), dim3(256), 0, stream,
                     points, x, neighbors, kpts, weights, out, ws);
  hipLaunchKernelGGL(finalize_kernel, dim3(1), dim3(128), 0, stream, ws, gamma, beta, ws + 2*C_OUT);
  hipLaunchKernelGGL(bn_lrelu_kernel, dim3(2048), dim3(256), 0, stream, out, ws + 2*C_OUT);
}